// Round 3
// baseline (736.204 us; speedup 1.0000x reference)
//
#include <hip/hip_runtime.h>
#include <hip/hip_bf16.h>

#define N_VOX 200000
#define KOFF 27
#define PPK 100000
#define NPAIRS (KOFF * PPK)
#define C 64
#define BN_EPS 1e-5f

typedef __bf16 bf16x8 __attribute__((ext_vector_type(8)));
typedef __bf16 bf16x4 __attribute__((ext_vector_type(4)));
typedef float f32x4 __attribute__((ext_vector_type(4)));

// ---------------------------------------------------------------------------
// features fp32 -> bf16 (RNE), vectorized.
// ---------------------------------------------------------------------------
__global__ __launch_bounds__(256)
void convert_features(const float* __restrict__ f, __bf16* __restrict__ fb)
{
    const size_t total4 = (size_t)N_VOX * C / 4;
    const size_t i = (size_t)blockIdx.x * blockDim.x + threadIdx.x;
    if (i >= total4) return;
    const float4 v = ((const float4*)f)[i];
    bf16x4 o;
    o.x = (__bf16)v.x; o.y = (__bf16)v.y; o.z = (__bf16)v.z; o.w = (__bf16)v.w;
    ((bf16x4*)fb)[i] = o;
}

// ---------------------------------------------------------------------------
// weight [k][cin][cout] fp32 -> wt [k][cout][cin] bf16 (transposed).
// ---------------------------------------------------------------------------
__global__ __launch_bounds__(256)
void convert_weight(const float* __restrict__ w, __bf16* __restrict__ wt)
{
    const int k = blockIdx.x;
    const float* W = w + (size_t)k * C * C;
    __bf16* Wt = wt + (size_t)k * C * C;
    for (int idx = threadIdx.x; idx < C * C; idx += 256) {
        const int ci = idx >> 6, co = idx & 63;
        Wt[co * C + ci] = (__bf16)W[idx];
    }
}

// ---------------------------------------------------------------------------
// Rulebook inversion step 1: histogram of out_idx (int atomics only).
// ---------------------------------------------------------------------------
__global__ __launch_bounds__(256)
void hist_kernel(const int* __restrict__ out_idx, int* __restrict__ cnt)
{
    const int i = blockIdx.x * 256 + threadIdx.x;
    if (i < NPAIRS) atomicAdd(&cnt[out_idx[i]], 1);
}

// ---------------------------------------------------------------------------
// Scan S1: per-block (1024 elems) sums of cnt.
// ---------------------------------------------------------------------------
__global__ __launch_bounds__(256)
void scan_block_sums(const int* __restrict__ cnt, int* __restrict__ bsum)
{
    __shared__ int s[256];
    const int t = threadIdx.x;
    const int i0 = blockIdx.x * 1024 + t * 4;
    int v = 0;
#pragma unroll
    for (int j = 0; j < 4; ++j) { const int i = i0 + j; if (i < N_VOX) v += cnt[i]; }
    s[t] = v;
    __syncthreads();
    for (int d = 128; d > 0; d >>= 1) {
        if (t < d) s[t] += s[t + d];
        __syncthreads();
    }
    if (t == 0) bsum[blockIdx.x] = s[0];
}

// ---------------------------------------------------------------------------
// Scan S2: exclusive scan of the (<=256) block sums, parallel in one block.
// ---------------------------------------------------------------------------
__global__ __launch_bounds__(256)
void scan_base(const int* __restrict__ bsum, int* __restrict__ bbase, int nblk)
{
    __shared__ int s[256];
    const int t = threadIdx.x;
    const int v = (t < nblk) ? bsum[t] : 0;
    s[t] = v;
    for (int d = 1; d < 256; d <<= 1) {
        __syncthreads();
        const int x = (t >= d) ? s[t - d] : 0;
        __syncthreads();
        s[t] += x;
    }
    if (t < nblk) bbase[t] = s[t] - v;
}

// ---------------------------------------------------------------------------
// Scan S3: exclusive offsets; writes offs (read-only later) + cursor (mutated
// by the GEMM's slot-claiming atomics).
// ---------------------------------------------------------------------------
__global__ __launch_bounds__(256)
void scan_write(const int* __restrict__ cnt, const int* __restrict__ bbase,
                int* __restrict__ offs, int* __restrict__ cursor)
{
    __shared__ int s[256];
    const int t = threadIdx.x;
    const int i0 = blockIdx.x * 1024 + t * 4;
    int v[4]; int local = 0;
#pragma unroll
    for (int j = 0; j < 4; ++j) {
        const int i = i0 + j;
        v[j] = (i < N_VOX) ? cnt[i] : 0;
        local += v[j];
    }
    s[t] = local;
    for (int d = 1; d < 256; d <<= 1) {
        __syncthreads();
        const int x = (t >= d) ? s[t - d] : 0;
        __syncthreads();
        s[t] += x;
    }
    int run = s[t] - local + bbase[blockIdx.x];
#pragma unroll
    for (int j = 0; j < 4; ++j) {
        const int i = i0 + j;
        if (i < N_VOX) { offs[i] = run; cursor[i] = run; run += v[j]; }
    }
}

// ---------------------------------------------------------------------------
// Conv GEMM (MFMA) -> bucket-sorted bf16 partial rows. No fp32 atomics:
// each pair claims a slot in its output voxel's run via one int atomic, the
// 64-ch partial row is repacked through LDS and stored as a contiguous 128B
// segment per half-wave (full-line writes, no RFO).
// ---------------------------------------------------------------------------
__global__ __launch_bounds__(256)
void conv_mfma_sorted(const __bf16* __restrict__ featb, const __bf16* __restrict__ wtb,
                      const int* __restrict__ in_idx, const int* __restrict__ out_idx,
                      int* __restrict__ cursor, __bf16* __restrict__ partial)
{
    constexpr int TP = 256;
    constexpr int STRIDE = 72;
    __shared__ __bf16 sA[TP * STRIDE];   // 36.9 KB (A tile, then reused for C repack)
    __shared__ int s_dest[TP];

    const int k = blockIdx.y;
    const int tile_base = blockIdx.x * TP;
    const int t = threadIdx.x;
    const int lane = t & 63;
    const int wave = t >> 6;
    const int m16 = lane & 15;
    const int quad = lane >> 4;

    // B fragments from Wt[k][cout][cin]
    const __bf16* Wt = wtb + (size_t)k * C * C;
    bf16x8 bfrag[4][2];
#pragma unroll
    for (int nt = 0; nt < 4; ++nt)
#pragma unroll
        for (int kc = 0; kc < 2; ++kc)
            bfrag[nt][kc] = *(const bf16x8*)(Wt + (nt * 16 + m16) * C + kc * 32 + quad * 8);

    // claim destination slots (1 int atomic per pair)
    {
        const int pair = tile_base + t;
        if (pair < PPK) {
            const int ov = out_idx[(size_t)k * PPK + pair];
            s_dest[t] = atomicAdd(&cursor[ov], 1);
        }
    }

    // stage gathered A rows (bf16) into LDS, coalesced dwordx4
    const int c8 = t & 7;
    const int r0 = t >> 3;
#pragma unroll
    for (int it = 0; it < 8; ++it) {
        const int r = r0 + it * 32;
        const int pair = tile_base + r;
        const int row = (pair < PPK) ? in_idx[(size_t)k * PPK + pair] : 0;
        const float4 v = *(const float4*)(featb + (size_t)row * C + c8 * 8);
        *(float4*)(sA + r * STRIDE + c8 * 8) = v;
    }
    __syncthreads();

    // MFMA: wave owns 64-pair stripe
    f32x4 acc[4][4] = {};
    const int mbase = wave * 64;
#pragma unroll
    for (int kc = 0; kc < 2; ++kc) {
        bf16x8 afrag[4];
#pragma unroll
        for (int mt = 0; mt < 4; ++mt)
            afrag[mt] = *(const bf16x8*)(sA + (mbase + mt * 16 + m16) * STRIDE + kc * 32 + quad * 8);
#pragma unroll
        for (int nt = 0; nt < 4; ++nt)
#pragma unroll
            for (int mt = 0; mt < 4; ++mt)
                acc[mt][nt] = __builtin_amdgcn_mfma_f32_16x16x32_bf16(
                    afrag[mt], bfrag[nt][kc], acc[mt][nt], 0, 0, 0);
    }
    __syncthreads();   // all sA reads done; safe to reuse as C staging

    // write acc rows into LDS as bf16 (C/D map: col=lane&15, row=quad*4+reg)
#pragma unroll
    for (int mt = 0; mt < 4; ++mt)
#pragma unroll
        for (int reg = 0; reg < 4; ++reg) {
            const int r = mbase + mt * 16 + quad * 4 + reg;
#pragma unroll
            for (int nt = 0; nt < 4; ++nt)
                sA[r * STRIDE + nt * 16 + m16] = (__bf16)acc[mt][nt][reg];
        }
    __syncthreads();

    // half-wave (32 lanes x 4B = one full 128B row) coalesced store to bucket slot
    const int hw = t >> 5;
    const int l2 = t & 31;
    for (int r = hw; r < TP; r += 8) {
        const int pair = tile_base + r;
        if (pair < PPK) {
            const unsigned v = *(const unsigned*)((const char*)sA + (size_t)r * STRIDE * 2 + l2 * 4);
            *(unsigned*)((char*)partial + (size_t)s_dest[r] * 128 + l2 * 4) = v;
        }
    }
}

// ---------------------------------------------------------------------------
// Gather-reduce over sorted runs + fused BN stats. Wave per voxel, lane per
// channel; entries are contiguous -> streaming 128B reads.
// ---------------------------------------------------------------------------
__global__ __launch_bounds__(256)
void reduce_stats(const __bf16* __restrict__ partial, const int* __restrict__ offs,
                  float* __restrict__ out, float* __restrict__ stats)
{
    __shared__ float ssum[256];
    __shared__ float ssq[256];
    const int t = threadIdx.x;
    const int lane = t & 63;
    const int wave = t >> 6;
    const int wglobal = blockIdx.x * 4 + wave;
    const int nw = gridDim.x * 4;
    const unsigned short* P = (const unsigned short*)partial;
    float s = 0.f, q = 0.f;
    for (int v = wglobal; v < N_VOX; v += nw) {
        const int b = offs[v];
        const int e = (v == N_VOX - 1) ? NPAIRS : offs[v + 1];
        float a0 = 0.f, a1 = 0.f;
        int i = b;
        for (; i + 1 < e; i += 2) {
            const unsigned u0 = P[(size_t)i * 64 + lane];
            const unsigned u1 = P[(size_t)(i + 1) * 64 + lane];
            a0 += __uint_as_float(u0 << 16);
            a1 += __uint_as_float(u1 << 16);
        }
        if (i < e) a0 += __uint_as_float((unsigned)P[(size_t)i * 64 + lane] << 16);
        const float a = a0 + a1;
        out[(size_t)v * 64 + lane] = a;
        s += a;
        q += a * a;
    }
    ssum[t] = s;
    ssq[t] = q;
    __syncthreads();
    if (wave == 0) {
        s = ssum[lane] + ssum[64 + lane] + ssum[128 + lane] + ssum[192 + lane];
        q = ssq[lane] + ssq[64 + lane] + ssq[128 + lane] + ssq[192 + lane];
        unsafeAtomicAdd(&stats[lane], s);
        unsafeAtomicAdd(&stats[64 + lane], q);
    }
}

// ---------------------------------------------------------------------------
// Fallback path (round-2): MFMA conv with fp32 atomic scatter + separate stats.
// Used only if ws_size can't hold the 346MB partial buffer.
// ---------------------------------------------------------------------------
__global__ __launch_bounds__(256)
void conv_mfma_atomic(const __bf16* __restrict__ featb, const __bf16* __restrict__ wtb,
                      const int* __restrict__ in_idx, const int* __restrict__ out_idx,
                      float* __restrict__ out)
{
    constexpr int TP = 256;
    constexpr int STRIDE = 72;
    __shared__ __bf16 sA[TP * STRIDE];
    __shared__ int s_out[TP];
    const int k = blockIdx.y;
    const int tile_base = blockIdx.x * TP;
    const int t = threadIdx.x;
    const int lane = t & 63;
    const int wave = t >> 6;
    const int m16 = lane & 15;
    const int quad = lane >> 4;
    const __bf16* Wt = wtb + (size_t)k * C * C;
    bf16x8 bfrag[4][2];
#pragma unroll
    for (int nt = 0; nt < 4; ++nt)
#pragma unroll
        for (int kc = 0; kc < 2; ++kc)
            bfrag[nt][kc] = *(const bf16x8*)(Wt + (nt * 16 + m16) * C + kc * 32 + quad * 8);
    {
        const int pair = tile_base + t;
        s_out[t] = (pair < PPK) ? out_idx[(size_t)k * PPK + pair] : 0;
    }
    const int c8 = t & 7;
    const int r0 = t >> 3;
#pragma unroll
    for (int it = 0; it < 8; ++it) {
        const int r = r0 + it * 32;
        const int pair = tile_base + r;
        const int row = (pair < PPK) ? in_idx[(size_t)k * PPK + pair] : 0;
        const float4 v = *(const float4*)(featb + (size_t)row * C + c8 * 8);
        *(float4*)(sA + r * STRIDE + c8 * 8) = v;
    }
    __syncthreads();
    f32x4 acc[4][4] = {};
    const int mbase = wave * 64;
#pragma unroll
    for (int kc = 0; kc < 2; ++kc) {
        bf16x8 afrag[4];
#pragma unroll
        for (int mt = 0; mt < 4; ++mt)
            afrag[mt] = *(const bf16x8*)(sA + (mbase + mt * 16 + m16) * STRIDE + kc * 32 + quad * 8);
#pragma unroll
        for (int nt = 0; nt < 4; ++nt)
#pragma unroll
            for (int mt = 0; mt < 4; ++mt)
                acc[mt][nt] = __builtin_amdgcn_mfma_f32_16x16x32_bf16(
                    afrag[mt], bfrag[nt][kc], acc[mt][nt], 0, 0, 0);
    }
#pragma unroll
    for (int mt = 0; mt < 4; ++mt)
#pragma unroll
        for (int reg = 0; reg < 4; ++reg) {
            const int r = mbase + mt * 16 + quad * 4 + reg;
            const int pair = tile_base + r;
            if (pair < PPK) {
                float* orow = out + (size_t)s_out[r] * C + m16;
#pragma unroll
                for (int nt = 0; nt < 4; ++nt)
                    unsafeAtomicAdd(orow + nt * 16, acc[mt][nt][reg]);
            }
        }
}

__global__ __launch_bounds__(256)
void stats_kernel(const float* __restrict__ out, float* __restrict__ stats,
                  int rows_per_block)
{
    __shared__ float ssum[256];
    __shared__ float ssq[256];
    const int c = threadIdx.x & 63;
    const int sub = threadIdx.x >> 6;
    const int row0 = blockIdx.x * rows_per_block;
    const int row1 = min(row0 + rows_per_block, N_VOX);
    float s = 0.f, q = 0.f;
    for (int r = row0 + sub; r < row1; r += 4) {
        const float v = out[(size_t)r * C + c];
        s += v; q += v * v;
    }
    ssum[threadIdx.x] = s;
    ssq[threadIdx.x] = q;
    __syncthreads();
    if (sub == 0) {
        s = ssum[c] + ssum[64 + c] + ssum[128 + c] + ssum[192 + c];
        q = ssq[c] + ssq[64 + c] + ssq[128 + c] + ssq[192 + c];
        unsafeAtomicAdd(&stats[c], s);
        unsafeAtomicAdd(&stats[64 + c], q);
    }
}

// ---------------------------------------------------------------------------
// BN finalize + apply (bias cancels under BN; never added).
// ---------------------------------------------------------------------------
__global__ void finalize_params(const float* __restrict__ stats,
                                const float* __restrict__ gamma,
                                const float* __restrict__ beta,
                                float* __restrict__ ss)
{
    const int c = threadIdx.x;
    const float inv_n = 1.0f / (float)N_VOX;
    const float mean = stats[c] * inv_n;
    const float var = stats[64 + c] * inv_n - mean * mean;
    const float scale = rsqrtf(var + BN_EPS) * gamma[c];
    ss[c] = scale;
    ss[64 + c] = beta[c] - mean * scale;
}

__global__ __launch_bounds__(256)
void norm_kernel(float* __restrict__ out, const float* __restrict__ ss)
{
    const size_t total4 = (size_t)N_VOX * C / 4;
    const size_t idx = (size_t)blockIdx.x * blockDim.x + threadIdx.x;
    if (idx >= total4) return;
    const int c4 = (int)(idx & 15);
    float4 v = ((const float4*)out)[idx];
    const float4 sc = ((const float4*)ss)[c4];
    const float4 sh = ((const float4*)(ss + 64))[c4];
    v.x = fmaxf(v.x * sc.x + sh.x, 0.f);
    v.y = fmaxf(v.y * sc.y + sh.y, 0.f);
    v.z = fmaxf(v.z * sc.z + sh.z, 0.f);
    v.w = fmaxf(v.w * sc.w + sh.w, 0.f);
    ((float4*)out)[idx] = v;
}

extern "C" void kernel_launch(void* const* d_in, const int* in_sizes, int n_in,
                              void* d_out, int out_size, void* d_ws, size_t ws_size,
                              hipStream_t stream)
{
    const float* features = (const float*)d_in[0];
    const float* weight   = (const float*)d_in[1];
    // d_in[2] = bias: cancels exactly under BatchNorm — unused.
    const float* gamma    = (const float*)d_in[3];
    const float* beta     = (const float*)d_in[4];
    const int*   in_idx   = (const int*)d_in[5];
    const int*   out_idx  = (const int*)d_in[6];
    float* out = (float*)d_out;

    // ---- workspace layout (256B-aligned regions) ----
    char* base = (char*)d_ws;
    size_t cur = 0;
    auto alloc = [&](size_t bytes) -> char* {
        char* p = base + cur;
        cur = (cur + bytes + 255) & ~(size_t)255;
        return p;
    };
    __bf16* featb  = (__bf16*)alloc((size_t)N_VOX * C * 2);      // 25.6 MB
    __bf16* wtb    = (__bf16*)alloc((size_t)KOFF * C * C * 2);   // 221 KB
    float*  stats  = (float*)alloc(128 * 4);
    float*  ss     = (float*)alloc(128 * 4);
    int*    cnt    = (int*)alloc((size_t)N_VOX * 4);             // 800 KB
    int*    offs   = (int*)alloc((size_t)N_VOX * 4);
    int*    cursor = (int*)alloc((size_t)N_VOX * 4);
    int*    bsum   = (int*)alloc(256 * 4);
    int*    bbase  = (int*)alloc(256 * 4);
    size_t fast_head = cur;
    __bf16* partial = (__bf16*)alloc((size_t)NPAIRS * C * 2);    // 345.6 MB
    const bool fast = (ws_size >= cur);

    const size_t total4 = (size_t)N_VOX * C / 4;
    const int nb_elem = (int)((total4 + 255) / 256);

    hipMemsetAsync(stats, 0, 128 * sizeof(float), stream);
    convert_features<<<nb_elem, 256, 0, stream>>>(features, featb);
    convert_weight<<<KOFF, 256, 0, stream>>>(weight, wtb);

    dim3 cgrid((PPK + 255) / 256, KOFF);   // 391 x 27

    if (fast) {
        (void)fast_head;
        hipMemsetAsync(cnt, 0, (size_t)N_VOX * 4, stream);
        hist_kernel<<<(NPAIRS + 255) / 256, 256, 0, stream>>>(out_idx, cnt);
        const int nscan = (N_VOX + 1023) / 1024;   // 196
        scan_block_sums<<<nscan, 256, 0, stream>>>(cnt, bsum);
        scan_base<<<1, 256, 0, stream>>>(bsum, bbase, nscan);
        scan_write<<<nscan, 256, 0, stream>>>(cnt, bbase, offs, cursor);
        conv_mfma_sorted<<<cgrid, 256, 0, stream>>>(featb, wtb, in_idx, out_idx,
                                                    cursor, partial);
        reduce_stats<<<512, 256, 0, stream>>>(partial, offs, out, stats);
    } else {
        hipMemsetAsync(out, 0, (size_t)N_VOX * C * sizeof(float), stream);
        conv_mfma_atomic<<<cgrid, 256, 0, stream>>>(featb, wtb, in_idx, out_idx, out);
        const int rpb = (N_VOX + 511) / 512;
        stats_kernel<<<512, 256, 0, stream>>>(out, stats, rpb);
    }

    finalize_params<<<1, 64, 0, stream>>>(stats, gamma, beta, ss);
    norm_kernel<<<nb_elem, 256, 0, stream>>>(out, ss);
}